// Round 2
// baseline (4840.971 us; speedup 1.0000x reference)
//
#include <hip/hip_runtime.h>
#include <math.h>

#define K_NN 20
#define NEG_SLOPE 0.2f

constexpr int NSEG = 4;     // coarse j-segments per query block
constexpr int QB   = 128;   // queries per block
constexpr int PT   = 128;   // points per tile
// 256 threads, 8x8 register tile per thread; selection = 128 q x 2 psegs
// partial-list count per query = NSEG * 2 = 8  (same ws layout as round 1)

// ---------------------------------------------------------------------------
// sq[i] = sum_c x[i][c]^2   (ascending-c FMA chain; must match dot order)
template<int C>
__global__ __launch_bounds__(256) void sqnorm_kernel(const float* __restrict__ x,
                                                     float* __restrict__ sq, int N) {
    int i = blockIdx.x * 256 + threadIdx.x;
    if (i < N) {
        float s = 0.f;
#pragma unroll
        for (int c = 0; c < C; ++c) { float v = x[i * C + c]; s += v * v; }
        sq[i] = s;
    }
}

// ---------------------------------------------------------------------------
// Tiled kNN: block = (QB queries) x (segment of points), 8x8 register tiles.
// LDS union: stage {qT swizzled, pT} overlaid with thread-major Dt.
template<int C>
__global__ __launch_bounds__(256) void knn_tiled_kernel(const float* __restrict__ x,
                                                        const float* __restrict__ sq,
                                                        float* __restrict__ pdist,
                                                        int* __restrict__ pidx, int N) {
    struct Stage { float qT[C][140]; float pT[C][128]; };
    union Smem { Stage s; float Dt[256][68]; };
    __shared__ Smem u;
    __shared__ float qsq_s[QB];
    __shared__ float psq_s[PT];

    const int tid  = threadIdx.x;
    const int qblk = blockIdx.x / NSEG;
    const int gseg = blockIdx.x % NSEG;
    const int q0   = qblk * QB;
    const int segLen = N / NSEG;
    const int j0   = gseg * segLen;

    // compute mapping: 16 qgroups x 16 pgroups, 8 each
    const int qg   = tid & 15;
    const int pg   = tid >> 4;
    const int qcol = qg * 8 + (qg >> 2) * 4;   // swizzled base col in qT

    // selection mapping: 128 queries x 2 point-halves
    const int sq_ = tid & 127;
    const int sps = tid >> 7;
    const int sqg = sq_ >> 3;
    const int si  = sq_ & 7;

    float dl[K_NN]; int il[K_NN];
#pragma unroll
    for (int p = 0; p < K_NN; ++p) { dl[p] = __builtin_inff(); il[p] = 0; }

    if (tid < QB) qsq_s[tid] = sq[q0 + tid];   // visible after first barrier

    const int nTiles = segLen / PT;
    for (int t = 0; t < nTiles; ++t) {
        const int jb = j0 + t * PT;
        // ---- stage qT (swizzled cols: q + 4*(q>>5)) and pT (plain) ----
#pragma unroll 4
        for (int uu = tid; uu < C * QB; uu += 256) {
            int qq = uu & (QB - 1);
            int c  = uu >> 7;
            u.s.qT[c][qq + 4 * (qq >> 5)] = x[(long)(q0 + qq) * C + c];
        }
#pragma unroll 4
        for (int uu = tid; uu < C * PT; uu += 256) {
            int pp = uu & (PT - 1);
            int c  = uu >> 7;
            u.s.pT[c][pp] = x[(long)(jb + pp) * C + c];
        }
        if (tid < PT) psq_s[tid] = sq[jb + tid];
        __syncthreads();

        // ---- compute 8x8 dot tile (ascending c — matches sqnorm rounding) ----
        float acc[8][8];
#pragma unroll
        for (int i = 0; i < 8; ++i)
#pragma unroll
            for (int j = 0; j < 8; ++j) acc[i][j] = 0.f;

#pragma unroll 2
        for (int c = 0; c < C; ++c) {
            float4 qa = *(const float4*)&u.s.qT[c][qcol];
            float4 qb = *(const float4*)&u.s.qT[c][qcol + 4];
            float4 pa = *(const float4*)&u.s.pT[c][pg * 8];
            float4 pb = *(const float4*)&u.s.pT[c][pg * 8 + 4];
            float qf[8] = {qa.x, qa.y, qa.z, qa.w, qb.x, qb.y, qb.z, qb.w};
            float pf[8] = {pa.x, pa.y, pa.z, pa.w, pb.x, pb.y, pb.z, pb.w};
#pragma unroll
            for (int i = 0; i < 8; ++i)
#pragma unroll
                for (int j = 0; j < 8; ++j)
                    acc[i][j] += qf[i] * pf[j];
        }
        __syncthreads();   // qT/pT reads done; union becomes Dt

        // ---- combine and write Dt (thread-major, contiguous per thread) ----
#pragma unroll
        for (int i = 0; i < 8; ++i) {
            float qs = qsq_s[qg * 8 + i];
#pragma unroll
            for (int j = 0; j < 8; ++j) {
                u.Dt[tid][i * 8 + j] = (qs - 2.f * acc[i][j]) + psq_s[pg * 8 + j];
            }
        }
        __syncthreads();

        // ---- selection: thread (sq_, sps) scans its 64 points, ascending p ----
        for (int pg8 = 0; pg8 < 8; ++pg8) {
            const int prow = sps * 8 + pg8;                 // point group index
            const float* drow = &u.Dt[sqg + 16 * prow][si * 8];
#pragma unroll
            for (int j8 = 0; j8 < 8; ++j8) {
                float d = drow[j8];
                if (d < dl[K_NN - 1]) {
                    dl[K_NN - 1] = d;
                    il[K_NN - 1] = jb + prow * 8 + j8;
#pragma unroll
                    for (int p = K_NN - 1; p > 0; --p) {
                        if (dl[p] < dl[p - 1]) {
                            float td = dl[p]; dl[p] = dl[p - 1]; dl[p - 1] = td;
                            int   ti = il[p]; il[p] = il[p - 1]; il[p - 1] = ti;
                        }
                    }
                }
            }
        }
        __syncthreads();   // Dt reads done before next stage overwrites union
    }

    const long base = ((long)(q0 + sq_) * 8 + (gseg * 2 + sps)) * K_NN;
#pragma unroll
    for (int p = 0; p < K_NN; ++p) { pdist[base + p] = dl[p]; pidx[base + p] = il[p]; }
}

// ---------------------------------------------------------------------------
// Merge 8 sorted partial lists -> final top-20 indices per query.
__global__ __launch_bounds__(256) void knn_merge_kernel(const float* __restrict__ pdist,
                                                        const int* __restrict__ pidx,
                                                        int* __restrict__ knn, int N) {
    int q = blockIdx.x * 256 + threadIdx.x;
    if (q >= N) return;
    float dl[K_NN]; int il[K_NN];
#pragma unroll
    for (int p = 0; p < K_NN; ++p) { dl[p] = __builtin_inff(); il[p] = 0; }

    for (int s = 0; s < 8; ++s) {
        const long base = ((long)q * 8 + s) * K_NN;
        for (int p = 0; p < K_NN; ++p) {
            float d = pdist[base + p];
            if (!(d < dl[K_NN - 1])) break;  // partial list sorted ascending
            int id = pidx[base + p];
            dl[K_NN - 1] = d; il[K_NN - 1] = id;
#pragma unroll
            for (int u = K_NN - 1; u > 0; --u) {
                if (dl[u] < dl[u - 1]) {
                    float td = dl[u]; dl[u] = dl[u - 1]; dl[u - 1] = td;
                    int   ti = il[u]; il[u] = il[u - 1]; il[u - 1] = ti;
                }
            }
        }
    }
#pragma unroll
    for (int p = 0; p < K_NN; ++p) knn[(long)q * K_NN + p] = il[p];
}

// ---------------------------------------------------------------------------
// A[i][f] = b[f] + sum_c x[i][c]*W[c][f] ;  U[i][f] = sum_c x[i][c]*W[C+c][f]
template<int C, int F>
__global__ __launch_bounds__(256) void proj_kernel(const float* __restrict__ x,
                                                   const float* __restrict__ W,
                                                   const float* __restrict__ b,
                                                   float* __restrict__ A,
                                                   float* __restrict__ U, int N) {
    int gid = blockIdx.x * 256 + threadIdx.x;
    int i = gid / F, f = gid % F;
    if (i >= N) return;
    float a = b[f], u = 0.f;
#pragma unroll
    for (int c = 0; c < C; ++c) {
        float xv = x[i * C + c];
        a += xv * W[c * F + f];
        u += xv * W[(C + c) * F + f];
    }
    A[(long)i * F + f] = a;
    U[(long)i * F + f] = u;
}

// ---------------------------------------------------------------------------
// out[i][f] = max_k leaky_relu(A[i][f] - U[i][f] + U[knn[i][k]][f])
template<int F>
__global__ __launch_bounds__(256) void agg_kernel(const float* __restrict__ A,
                                                  const float* __restrict__ U,
                                                  const int* __restrict__ knn,
                                                  float* __restrict__ out, int N) {
    int gid = blockIdx.x * 256 + threadIdx.x;
    int i = gid / F, f = gid % F;
    if (i >= N) return;
    float a = A[(long)i * F + f] - U[(long)i * F + f];
    float m = -__builtin_inff();
#pragma unroll
    for (int k = 0; k < K_NN; ++k) {
        int j = knn[(long)i * K_NN + k];
        float v = a + U[(long)j * F + f];
        v = fmaxf(v, v * NEG_SLOPE);  // leaky_relu (slope 0.2 > 0)
        m = fmaxf(m, v);
    }
    out[(long)i * F + f] = m;
}

// ---------------------------------------------------------------------------
extern "C" void kernel_launch(void* const* d_in, const int* in_sizes, int n_in,
                              void* d_out, int out_size, void* d_ws, size_t ws_size,
                              hipStream_t stream) {
    const float* x  = (const float*)d_in[0];
    const float* W1 = (const float*)d_in[1];
    const float* b1 = (const float*)d_in[2];
    const float* W2 = (const float*)d_in[3];
    const float* b2 = (const float*)d_in[4];
    const float* W3 = (const float*)d_in[5];
    const float* b3 = (const float*)d_in[6];
    const int N = in_sizes[0] / 3;  // 16384

    // workspace layout (same footprint as round 1)
    float* ws  = (float*)d_ws;
    float* sq  = ws;                                  // N
    float* pd  = sq + N;                              // N*8*K_NN
    float* A   = pd + (size_t)N * 8 * K_NN;           // N*128
    float* U   = A + (size_t)N * 128;                 // N*128
    float* h1  = U + (size_t)N * 128;                 // N*64
    float* h2  = h1 + (size_t)N * 64;                 // N*64
    int* pidx  = (int*)(h2 + (size_t)N * 64);         // N*8*K_NN
    int* knn   = pidx + (size_t)N * 8 * K_NN;         // N*K_NN
    float* out = (float*)d_out;

    const int qBlocks   = N / 256;
    const int knnBlocks = (N / QB) * NSEG;            // 512

    // ---- Layer 1 (C=3 -> F=64) ----
    sqnorm_kernel<3><<<qBlocks, 256, 0, stream>>>(x, sq, N);
    knn_tiled_kernel<3><<<knnBlocks, 256, 0, stream>>>(x, sq, pd, pidx, N);
    knn_merge_kernel<<<qBlocks, 256, 0, stream>>>(pd, pidx, knn, N);
    proj_kernel<3, 64><<<(N * 64) / 256, 256, 0, stream>>>(x, W1, b1, A, U, N);
    agg_kernel<64><<<(N * 64) / 256, 256, 0, stream>>>(A, U, knn, h1, N);

    // ---- Layer 2 (C=64 -> F=64) ----
    sqnorm_kernel<64><<<qBlocks, 256, 0, stream>>>(h1, sq, N);
    knn_tiled_kernel<64><<<knnBlocks, 256, 0, stream>>>(h1, sq, pd, pidx, N);
    knn_merge_kernel<<<qBlocks, 256, 0, stream>>>(pd, pidx, knn, N);
    proj_kernel<64, 64><<<(N * 64) / 256, 256, 0, stream>>>(h1, W2, b2, A, U, N);
    agg_kernel<64><<<(N * 64) / 256, 256, 0, stream>>>(A, U, knn, h2, N);

    // ---- Layer 3 (C=64 -> F=128) ----
    sqnorm_kernel<64><<<qBlocks, 256, 0, stream>>>(h2, sq, N);
    knn_tiled_kernel<64><<<knnBlocks, 256, 0, stream>>>(h2, sq, pd, pidx, N);
    knn_merge_kernel<<<qBlocks, 256, 0, stream>>>(pd, pidx, knn, N);
    proj_kernel<64, 128><<<(N * 128) / 256, 256, 0, stream>>>(h2, W3, b3, A, U, N);
    agg_kernel<128><<<(N * 128) / 256, 256, 0, stream>>>(A, U, knn, out, N);
}

// Round 3
// 4557.418 us; speedup vs baseline: 1.0622x; 1.0622x over previous
//
#include <hip/hip_runtime.h>
#include <math.h>

#define K_NN 20
#define NEG_SLOPE 0.2f

constexpr int L1SEG = 8;   // segments for fused (layer-1 / fallback) kNN
constexpr int TJ    = 128; // point tile for fused kNN

// ---------------------------------------------------------------------------
__device__ __forceinline__ void insert_sorted(float (&dl)[K_NN], int (&il)[K_NN],
                                              float d, int idx) {
    if (d < dl[K_NN - 1]) {
        dl[K_NN - 1] = d; il[K_NN - 1] = idx;
#pragma unroll
        for (int p = K_NN - 1; p > 0; --p) {
            if (dl[p] < dl[p - 1]) {   // strict <: earlier (lower-index) ties stay first
                float td = dl[p]; dl[p] = dl[p - 1]; dl[p - 1] = td;
                int   ti = il[p]; il[p] = il[p - 1]; il[p - 1] = ti;
            }
        }
    }
}

// ---------------------------------------------------------------------------
// sq[i] = sum_c x[i][c]^2   (ascending-c FMA chain; must match dot order)
template<int C>
__global__ __launch_bounds__(256) void sqnorm_kernel(const float* __restrict__ x,
                                                     float* __restrict__ sq, int N) {
    int i = blockIdx.x * 256 + threadIdx.x;
    if (i < N) {
        float s = 0.f;
#pragma unroll
        for (int c = 0; c < C; ++c) { float v = x[i * C + c]; s += v * v; }
        sq[i] = s;
    }
}

// ---------------------------------------------------------------------------
// Fused per-segment kNN (round-1 proven): 1 thread = 1 query, broadcast LDS tile.
// Used for layer 1 (C=3) always, and for C=64 only as ws-too-small fallback.
template<int C>
__global__ __launch_bounds__(256) void knn_partial_kernel(const float* __restrict__ x,
                                                          const float* __restrict__ sq,
                                                          float* __restrict__ pdist,
                                                          int* __restrict__ pidx, int N) {
    __shared__ float tile[TJ * C];
    __shared__ float tsq[TJ];

    const int qblk = blockIdx.x / L1SEG;
    const int seg  = blockIdx.x % L1SEG;
    const int q    = qblk * 256 + threadIdx.x;
    const int segLen = N / L1SEG;
    const int j0   = seg * segLen;

    float qf[C];
#pragma unroll
    for (int c = 0; c < C; ++c) qf[c] = x[q * C + c];
    const float qsq = sq[q];

    float dl[K_NN]; int il[K_NN];
#pragma unroll
    for (int p = 0; p < K_NN; ++p) { dl[p] = __builtin_inff(); il[p] = 0; }

    for (int t0 = 0; t0 < segLen; t0 += TJ) {
        __syncthreads();
        for (int u = threadIdx.x; u < TJ * C; u += 256)
            tile[u] = x[(j0 + t0) * C + u];
        for (int u = threadIdx.x; u < TJ; u += 256)
            tsq[u] = sq[j0 + t0 + u];
        __syncthreads();

        for (int t = 0; t < TJ; ++t) {
            float dot = 0.f;
#pragma unroll
            for (int c = 0; c < C; ++c) dot += qf[c] * tile[t * C + c];
            float d = qsq - 2.f * dot + tsq[t];
            insert_sorted(dl, il, d, j0 + t0 + t);
        }
    }

    const long base = ((long)q * L1SEG + seg) * K_NN;
#pragma unroll
    for (int p = 0; p < K_NN; ++p) { pdist[base + p] = dl[p]; pidx[base + p] = il[p]; }
}

// ---------------------------------------------------------------------------
// xT[c][i] = x[i][c]  (C = 64). Reads L2-absorbed (4MB), writes coalesced.
__global__ __launch_bounds__(256) void transpose64_kernel(const float* __restrict__ xin,
                                                          float* __restrict__ xT, int N) {
    int i = blockIdx.x * 256 + threadIdx.x;
    int c = blockIdx.y;
    xT[(size_t)c * N + i] = xin[(size_t)i * 64 + c];
}

// ---------------------------------------------------------------------------
// Distance GEMM tile: 128 queries x 128 points, 8x8 per thread, C = 64.
// Feature-major LDS staged coalesced from xT; point columns swizzled
// s(p) = p + 4*(p>>5) for conflict-free ds_read_b128.
__global__ __launch_bounds__(256) void dist_kernel(const float* __restrict__ xT,
                                                   const float* __restrict__ sq,
                                                   float* __restrict__ D,
                                                   int N, int segLen, int j0, int pbBits) {
    __shared__ float qT[64][128];
    __shared__ float pT[64][140];
    __shared__ float qsq_s[128];
    __shared__ float psq_s[140];

    const int tid = threadIdx.x;
    const int qb  = blockIdx.x >> pbBits;
    const int pb  = blockIdx.x & ((1 << pbBits) - 1);
    const int q0  = qb * 128;
    const int p0  = pb * 128;   // local column base within segment

#pragma unroll
    for (int k = 0; k < 8; ++k) {
        int idx = tid + 256 * k;
        int c   = idx >> 5;
        int ch  = idx & 31;
        float4 qv = *(const float4*)&xT[(size_t)c * N + q0 + ch * 4];
        *(float4*)&qT[c][ch * 4] = qv;
        float4 pv = *(const float4*)&xT[(size_t)c * N + j0 + p0 + ch * 4];
        *(float4*)&pT[c][ch * 4 + 4 * (ch >> 3)] = pv;   // s(4*ch)
    }
    if (tid < 128) {
        qsq_s[tid] = sq[q0 + tid];
    } else {
        int t = tid - 128;
        psq_s[t + 4 * (t >> 5)] = sq[j0 + p0 + t];       // swizzled like pT
    }
    __syncthreads();

    const int qg   = tid >> 4;                 // 0..15 (broadcast qT reads)
    const int pg   = tid & 15;                 // 0..15 (swizzled pT reads)
    const int qcol = qg * 8;
    const int pcol = pg * 8 + 4 * (pg >> 2);   // s(pg*8)

    float acc[8][8];
#pragma unroll
    for (int i = 0; i < 8; ++i)
#pragma unroll
        for (int j = 0; j < 8; ++j) acc[i][j] = 0.f;

#pragma unroll 4
    for (int c = 0; c < 64; ++c) {
        float4 qa  = *(const float4*)&qT[c][qcol];
        float4 qb4 = *(const float4*)&qT[c][qcol + 4];
        float4 pa  = *(const float4*)&pT[c][pcol];
        float4 pb4 = *(const float4*)&pT[c][pcol + 4];
        float qf[8] = {qa.x, qa.y, qa.z, qa.w, qb4.x, qb4.y, qb4.z, qb4.w};
        float pf[8] = {pa.x, pa.y, pa.z, pa.w, pb4.x, pb4.y, pb4.z, pb4.w};
#pragma unroll
        for (int i = 0; i < 8; ++i)
#pragma unroll
            for (int j = 0; j < 8; ++j) acc[i][j] += qf[i] * pf[j];
    }

#pragma unroll
    for (int i = 0; i < 8; ++i) {
        float qs = qsq_s[qcol + i];
        float* drow = D + (size_t)(q0 + qcol + i) * segLen + p0 + pg * 8;
        float4 o0, o1;
        o0.x = (qs - 2.f * acc[i][0]) + psq_s[pcol + 0];
        o0.y = (qs - 2.f * acc[i][1]) + psq_s[pcol + 1];
        o0.z = (qs - 2.f * acc[i][2]) + psq_s[pcol + 2];
        o0.w = (qs - 2.f * acc[i][3]) + psq_s[pcol + 3];
        o1.x = (qs - 2.f * acc[i][4]) + psq_s[pcol + 4];
        o1.y = (qs - 2.f * acc[i][5]) + psq_s[pcol + 5];
        o1.z = (qs - 2.f * acc[i][6]) + psq_s[pcol + 6];
        o1.w = (qs - 2.f * acc[i][7]) + psq_s[pcol + 7];
        *(float4*)&drow[0] = o0;
        *(float4*)&drow[4] = o1;
    }
}

// ---------------------------------------------------------------------------
// Per-segment top-20 from materialized distances. 1 wave per query.
// Per-lane register top-20 over contiguous sub-range, then 20 rounds of
// wave-wide lex arg-min (d, idx) via shfl_xor. Output sorted ascending.
__global__ __launch_bounds__(256) void select_kernel(const float* __restrict__ D,
                                                     float* __restrict__ pdist,
                                                     int* __restrict__ pidx,
                                                     int N, int segLen, int j0,
                                                     int seg, int nseg) {
    __shared__ float runs[4][64 * 42];   // stride 42 words: conflict-free lanes
    const int tid = threadIdx.x;
    const int w = tid >> 6;
    const int l = tid & 63;
    const int q = blockIdx.x * 4 + w;
    const int perLane = segLen >> 6;

    const float* row = D + (size_t)q * segLen + l * perLane;
    float dl[K_NN]; int il[K_NN];
#pragma unroll
    for (int p = 0; p < K_NN; ++p) { dl[p] = __builtin_inff(); il[p] = 0; }

    const int ibase = j0 + l * perLane;
    for (int k = 0; k < perLane; k += 4) {
        float4 v = *(const float4*)&row[k];
        insert_sorted(dl, il, v.x, ibase + k);
        insert_sorted(dl, il, v.y, ibase + k + 1);
        insert_sorted(dl, il, v.z, ibase + k + 2);
        insert_sorted(dl, il, v.w, ibase + k + 3);
    }

    float* myrun = &runs[w][l * 42];
#pragma unroll
    for (int p = 0; p < K_NN; ++p) {
        myrun[2 * p]     = dl[p];
        myrun[2 * p + 1] = __int_as_float(il[p]);
    }
    __syncthreads();

    int head = 0;
    const float* wrun = &runs[w][0];
    for (int t = 0; t < K_NN; ++t) {
        float bd; int bi;
        if (head < K_NN) {
            bd = wrun[l * 42 + 2 * head];
            bi = __float_as_int(wrun[l * 42 + 2 * head + 1]);
        } else { bd = __builtin_inff(); bi = 0x7fffffff; }
        int bl = l;
#pragma unroll
        for (int off = 1; off < 64; off <<= 1) {
            float od = __shfl_xor(bd, off);
            int   oi = __shfl_xor(bi, off);
            int   ol = __shfl_xor(bl, off);
            if (od < bd || (od == bd && oi < bi)) { bd = od; bi = oi; bl = ol; }
        }
        if (l == 0) {
            size_t ob = ((size_t)q * nseg + seg) * K_NN + t;
            pdist[ob] = bd; pidx[ob] = bi;
        }
        if (l == bl) ++head;
    }
}

// ---------------------------------------------------------------------------
// Merge nseg sorted partial lists -> final top-20 indices per query.
__global__ __launch_bounds__(256) void knn_merge_kernel(const float* __restrict__ pdist,
                                                        const int* __restrict__ pidx,
                                                        int* __restrict__ knn,
                                                        int N, int nseg) {
    int q = blockIdx.x * 256 + threadIdx.x;
    if (q >= N) return;
    float dl[K_NN]; int il[K_NN];
#pragma unroll
    for (int p = 0; p < K_NN; ++p) { dl[p] = __builtin_inff(); il[p] = 0; }

    for (int s = 0; s < nseg; ++s) {
        const long base = ((long)q * nseg + s) * K_NN;
        for (int p = 0; p < K_NN; ++p) {
            float d = pdist[base + p];
            if (!(d < dl[K_NN - 1])) break;  // partial list sorted ascending
            insert_sorted(dl, il, d, pidx[base + p]);
        }
    }
#pragma unroll
    for (int p = 0; p < K_NN; ++p) knn[(long)q * K_NN + p] = il[p];
}

// ---------------------------------------------------------------------------
// A[i][f] = b[f] + sum_c x[i][c]*W[c][f] ;  U[i][f] = sum_c x[i][c]*W[C+c][f]
template<int C, int F>
__global__ __launch_bounds__(256) void proj_kernel(const float* __restrict__ x,
                                                   const float* __restrict__ W,
                                                   const float* __restrict__ b,
                                                   float* __restrict__ A,
                                                   float* __restrict__ U, int N) {
    int gid = blockIdx.x * 256 + threadIdx.x;
    int i = gid / F, f = gid % F;
    if (i >= N) return;
    float a = b[f], u = 0.f;
#pragma unroll
    for (int c = 0; c < C; ++c) {
        float xv = x[i * C + c];
        a += xv * W[c * F + f];
        u += xv * W[(C + c) * F + f];
    }
    A[(long)i * F + f] = a;
    U[(long)i * F + f] = u;
}

// ---------------------------------------------------------------------------
// out[i][f] = max_k leaky_relu(A[i][f] - U[i][f] + U[knn[i][k]][f])
template<int F>
__global__ __launch_bounds__(256) void agg_kernel(const float* __restrict__ A,
                                                  const float* __restrict__ U,
                                                  const int* __restrict__ knn,
                                                  float* __restrict__ out, int N) {
    int gid = blockIdx.x * 256 + threadIdx.x;
    int i = gid / F, f = gid % F;
    if (i >= N) return;
    float a = A[(long)i * F + f] - U[(long)i * F + f];
    float m = -__builtin_inff();
#pragma unroll
    for (int k = 0; k < K_NN; ++k) {
        int j = knn[(long)i * K_NN + k];
        float v = a + U[(long)j * F + f];
        v = fmaxf(v, v * NEG_SLOPE);  // leaky_relu (slope 0.2 > 0)
        m = fmaxf(m, v);
    }
    out[(long)i * F + f] = m;
}

// ---------------------------------------------------------------------------
static void run_knn_matrix(const float* feat, float* xT, float* sq, float* D,
                           float* pd, int* pidx, int* knn, int N, int nseg,
                           hipStream_t stream) {
    sqnorm_kernel<64><<<N / 256, 256, 0, stream>>>(feat, sq, N);
    transpose64_kernel<<<dim3(N / 256, 64), 256, 0, stream>>>(feat, xT, N);
    int segLen  = N / nseg;
    int pbCount = segLen / 128;
    int pbBits  = 31 - __builtin_clz(pbCount);
    for (int s = 0; s < nseg; ++s) {
        dist_kernel<<<(N / 128) * pbCount, 256, 0, stream>>>(xT, sq, D, N, segLen,
                                                             s * segLen, pbBits);
        select_kernel<<<N / 4, 256, 0, stream>>>(D, pd, pidx, N, segLen,
                                                 s * segLen, s, nseg);
    }
    knn_merge_kernel<<<N / 256, 256, 0, stream>>>(pd, pidx, knn, N, nseg);
}

static void run_knn_fused(const float* feat, float* sq, float* pd, int* pidx,
                          int* knn, int N, hipStream_t stream) {
    sqnorm_kernel<64><<<N / 256, 256, 0, stream>>>(feat, sq, N);
    knn_partial_kernel<64><<<(N / 256) * L1SEG, 256, 0, stream>>>(feat, sq, pd, pidx, N);
    knn_merge_kernel<<<N / 256, 256, 0, stream>>>(pd, pidx, knn, N, L1SEG);
}

// ---------------------------------------------------------------------------
extern "C" void kernel_launch(void* const* d_in, const int* in_sizes, int n_in,
                              void* d_out, int out_size, void* d_ws, size_t ws_size,
                              hipStream_t stream) {
    const float* x  = (const float*)d_in[0];
    const float* W1 = (const float*)d_in[1];
    const float* b1 = (const float*)d_in[2];
    const float* W2 = (const float*)d_in[3];
    const float* b2 = (const float*)d_in[4];
    const float* W3 = (const float*)d_in[5];
    const float* b3 = (const float*)d_in[6];
    const int N = in_sizes[0] / 3;  // 16384

    float* ws = (float*)d_ws;
    float* sq = ws;                           // N
    float* A  = sq + N;                       // N*128
    float* U  = A + (size_t)N * 128;          // N*128
    float* h1 = U + (size_t)N * 128;          // N*64
    float* h2 = h1 + (size_t)N * 64;          // N*64
    float* out = (float*)d_out;

    // pick matrix path segmentation from available workspace
    const size_t baseW = (size_t)N * (1 + 128 + 128 + 64 + 64);
    const size_t wsW   = ws_size / 4;
    int nsegM = 0;
    {
        const int cands[2] = {8, 16};
        for (int ci = 0; ci < 2 && !nsegM; ++ci) {
            int ns = cands[ci];
            size_t need = baseW + (size_t)N * 64                 // xT
                        + (size_t)N * ns * K_NN * 2              // pd + pidx
                        + (size_t)N * K_NN                       // knn
                        + (size_t)N * (size_t)(N / ns);          // D
            if (need <= wsW) nsegM = ns;
        }
    }

    if (nsegM) {
        float* xT  = h2 + (size_t)N * 64;                        // N*64
        float* pd  = xT + (size_t)N * 64;                        // N*nsegM*20
        int* pidx  = (int*)(pd + (size_t)N * nsegM * K_NN);      // N*nsegM*20
        int* knn   = pidx + (size_t)N * nsegM * K_NN;            // N*20
        float* D   = (float*)(knn + (size_t)N * K_NN);           // N*(N/nsegM)

        // ---- Layer 1 (C=3 -> F=64): fused path ----
        sqnorm_kernel<3><<<N / 256, 256, 0, stream>>>(x, sq, N);
        knn_partial_kernel<3><<<(N / 256) * L1SEG, 256, 0, stream>>>(x, sq, pd, pidx, N);
        knn_merge_kernel<<<N / 256, 256, 0, stream>>>(pd, pidx, knn, N, L1SEG);
        proj_kernel<3, 64><<<(N * 64) / 256, 256, 0, stream>>>(x, W1, b1, A, U, N);
        agg_kernel<64><<<(N * 64) / 256, 256, 0, stream>>>(A, U, knn, h1, N);

        // ---- Layer 2 (C=64 -> F=64): matrix path ----
        run_knn_matrix(h1, xT, sq, D, pd, pidx, knn, N, nsegM, stream);
        proj_kernel<64, 64><<<(N * 64) / 256, 256, 0, stream>>>(h1, W2, b2, A, U, N);
        agg_kernel<64><<<(N * 64) / 256, 256, 0, stream>>>(A, U, knn, h2, N);

        // ---- Layer 3 (C=64 -> F=128): matrix path ----
        run_knn_matrix(h2, xT, sq, D, pd, pidx, knn, N, nsegM, stream);
        proj_kernel<64, 128><<<(N * 128) / 256, 256, 0, stream>>>(h2, W3, b3, A, U, N);
        agg_kernel<128><<<(N * 128) / 256, 256, 0, stream>>>(A, U, knn, out, N);
    } else {
        // ---- fallback: round-1 fused everywhere (small workspace) ----
        float* pd = h2 + (size_t)N * 64;                         // N*8*20
        int* pidx = (int*)(pd + (size_t)N * L1SEG * K_NN);
        int* knn  = pidx + (size_t)N * L1SEG * K_NN;

        sqnorm_kernel<3><<<N / 256, 256, 0, stream>>>(x, sq, N);
        knn_partial_kernel<3><<<(N / 256) * L1SEG, 256, 0, stream>>>(x, sq, pd, pidx, N);
        knn_merge_kernel<<<N / 256, 256, 0, stream>>>(pd, pidx, knn, N, L1SEG);
        proj_kernel<3, 64><<<(N * 64) / 256, 256, 0, stream>>>(x, W1, b1, A, U, N);
        agg_kernel<64><<<(N * 64) / 256, 256, 0, stream>>>(A, U, knn, h1, N);

        run_knn_fused(h1, sq, pd, pidx, knn, N, stream);
        proj_kernel<64, 64><<<(N * 64) / 256, 256, 0, stream>>>(h1, W2, b2, A, U, N);
        agg_kernel<64><<<(N * 64) / 256, 256, 0, stream>>>(A, U, knn, h2, N);

        run_knn_fused(h2, sq, pd, pidx, knn, N, stream);
        proj_kernel<64, 128><<<(N * 128) / 256, 256, 0, stream>>>(h2, W3, b3, A, U, N);
        agg_kernel<128><<<(N * 128) / 256, 256, 0, stream>>>(A, U, knn, out, N);
    }
}